// Round 1
// baseline (604.516 us; speedup 1.0000x reference)
//
#include <hip/hip_runtime.h>
#include <hip/hip_bf16.h>
#include <math.h>

#define BB 16
#define CC 64
#define NN 512
#define TT 128
#define JJ (NN*TT)   // 65536 columns per (b, channel) in the mix view
#define JT 128       // j-tile for mix kernel

// ---------------------------------------------------------------------------
// K1: k[b,c,t] = sum_i sig[b,c,i,t] * alpha[i]
// one block per (b,c); 256 threads = 8 i-subgroups x 32 t-quads (float4)
// ---------------------------------------------------------------------------
__global__ __launch_bounds__(256) void k_reduce_kernel(
    const float* __restrict__ sig, const float* __restrict__ alpha,
    float* __restrict__ kout)
{
    __shared__ float aS[NN];
    __shared__ float4 red[8][32];
    const int tid = threadIdx.x;
    for (int x = tid; x < NN; x += 256) aS[x] = alpha[x];
    __syncthreads();

    const int bc = blockIdx.x;
    const float* base = sig + (size_t)bc * (NN * TT);
    const int t4 = tid & 31;   // which float4 of the T=128 row
    const int ig = tid >> 5;   // i-subgroup 0..7

    float4 acc = make_float4(0.f, 0.f, 0.f, 0.f);
    for (int i = ig; i < NN; i += 8) {
        float4 v = *(const float4*)(base + i * TT + t4 * 4);
        const float a = aS[i];
        acc.x = fmaf(v.x, a, acc.x);
        acc.y = fmaf(v.y, a, acc.y);
        acc.z = fmaf(v.z, a, acc.z);
        acc.w = fmaf(v.w, a, acc.w);
    }
    red[ig][t4] = acc;
    __syncthreads();
    if (tid < 32) {
        float4 s = red[0][tid];
        #pragma unroll
        for (int g = 1; g < 8; g++) {
            float4 r = red[g][tid];
            s.x += r.x; s.y += r.y; s.z += r.z; s.w += r.w;
        }
        *(float4*)(kout + (size_t)bc * TT + tid * 4) = s;
    }
}

// ---------------------------------------------------------------------------
// K2a: kwT[b][s][c] = sum_t k[b][c][t] * Wc[t][s]   (stored transposed so K2b
// can read it with stride-1 per-lane LDS access)
// one block per batch
// ---------------------------------------------------------------------------
__global__ __launch_bounds__(256) void kw_kernel(
    const float* __restrict__ kin, const float* __restrict__ Wc,
    float* __restrict__ kwT)
{
    __shared__ float kl[CC * TT];  // 32 KiB
    const int b = blockIdx.x;
    const int tid = threadIdx.x;
    const float* kb = kin + b * CC * TT;
    for (int x = tid; x < CC * TT; x += 256) kl[x] = kb[x];
    __syncthreads();

    float* kwb = kwT + b * TT * CC;
    for (int x = tid; x < CC * TT; x += 256) {
        const int c = x >> 7;    // wave-uniform -> kl reads broadcast
        const int s = x & 127;   // per-lane -> Wc reads coalesced
        float acc = 0.f;
        for (int t = 0; t < TT; t++)
            acc = fmaf(kl[c * TT + t], Wc[t * TT + s], acc);
        kwb[s * CC + c] = acc;   // transposed scatter (tiny, L2 absorbs)
    }
}

// ---------------------------------------------------------------------------
// K2b: scores[c][d] = sum_s kwT[s][c] * k[d][s]; softmax over d -> att[b][c][d]
// one block per batch
// ---------------------------------------------------------------------------
__global__ __launch_bounds__(256) void attn_kernel(
    const float* __restrict__ kin, const float* __restrict__ kwT,
    float* __restrict__ att)
{
    __shared__ float kw[TT * CC];     // 32 KiB, [s][c]
    __shared__ float sc[CC * 65];     // padded rows: bank-conflict-free scatter
    const int b = blockIdx.x;
    const int tid = threadIdx.x;
    const float* kwb = kwT + b * TT * CC;
    for (int x = tid; x < TT * CC; x += 256) kw[x] = kwb[x];
    __syncthreads();

    const float* kb = kin + b * CC * TT;
    for (int x = tid; x < CC * CC; x += 256) {
        const int c = x & 63;   // per-lane -> kw[s*CC+c] stride-1, conflict-free
        const int d = x >> 6;   // wave-uniform -> kb[d*TT+s] broadcast (L1)
        float acc = 0.f;
        for (int s = 0; s < TT; s++)
            acc = fmaf(kw[s * CC + c], kb[d * TT + s], acc);
        sc[c * 65 + d] = acc;
    }
    __syncthreads();

    if (tid < CC) {
        const int c = tid;
        float m = -1e30f;
        for (int d = 0; d < CC; d++) m = fmaxf(m, sc[c * 65 + d]);
        float sum = 0.f;
        for (int d = 0; d < CC; d++) {
            const float e = __expf(sc[c * 65 + d] - m);
            sc[c * 65 + d] = e;
            sum += e;
        }
        const float inv = 1.f / sum;
        float* ab = att + b * CC * CC + c * CC;
        for (int d = 0; d < CC; d++) ab[d] = sc[c * 65 + d] * inv;
    }
}

// ---------------------------------------------------------------------------
// K3: out[b][c][j] = sum_i att[b][c][i] * sig[b][i][j],  j = n*T + t flattened
// grid = (JJ/JT, B); block 256. LDS: att (64x65 padded) + sig tile (64xJT).
// Each thread: 4c x 8j register tile (32 accumulators).
// ---------------------------------------------------------------------------
__global__ __launch_bounds__(256) void mix_kernel(
    const float* __restrict__ sig, const float* __restrict__ att,
    float* __restrict__ out)
{
    __shared__ float attL[CC][CC + 1];   // +1 pad: conflict-free strided reads
    __shared__ float stile[CC][JT];      // 32 KiB
    const int b = blockIdx.y;
    const int jbase = blockIdx.x * JT;
    const int tid = threadIdx.x;

    const float* ab = att + b * CC * CC;
    for (int x = tid; x < CC * CC; x += 256)
        attL[x >> 6][x & 63] = ab[x];

    const float* sb = sig + (size_t)b * CC * JJ + jbase;
    for (int x = tid; x < CC * JT / 4; x += 256) {
        const int i = x >> 5;   // JT/4 = 32 quads per row
        const int q = x & 31;
        *(float4*)(&stile[i][q * 4]) = *(const float4*)(sb + (size_t)i * JJ + q * 4);
    }
    __syncthreads();

    const int tc = tid >> 4;   // 0..15 -> channels 4*tc .. 4*tc+3
    const int tj = tid & 15;   // quads tj and tj+16

    float4 acc[4][2];
    #pragma unroll
    for (int q = 0; q < 4; q++) {
        acc[q][0] = make_float4(0.f, 0.f, 0.f, 0.f);
        acc[q][1] = make_float4(0.f, 0.f, 0.f, 0.f);
    }

    for (int i = 0; i < CC; i++) {
        float a[4];
        #pragma unroll
        for (int q = 0; q < 4; q++) a[q] = attL[4 * tc + q][i];
        #pragma unroll
        for (int u = 0; u < 2; u++) {
            const float4 s = *(const float4*)(&stile[i][(tj + 16 * u) * 4]);
            #pragma unroll
            for (int q = 0; q < 4; q++) {
                acc[q][u].x = fmaf(a[q], s.x, acc[q][u].x);
                acc[q][u].y = fmaf(a[q], s.y, acc[q][u].y);
                acc[q][u].z = fmaf(a[q], s.z, acc[q][u].z);
                acc[q][u].w = fmaf(a[q], s.w, acc[q][u].w);
            }
        }
    }

    float* ob = out + (size_t)b * CC * JJ + jbase;
    #pragma unroll
    for (int q = 0; q < 4; q++) {
        const int c = 4 * tc + q;
        #pragma unroll
        for (int u = 0; u < 2; u++)
            *(float4*)(ob + (size_t)c * JJ + (tj + 16 * u) * 4) = acc[q][u];
    }
}

// ---------------------------------------------------------------------------
extern "C" void kernel_launch(void* const* d_in, const int* in_sizes, int n_in,
                              void* d_out, int out_size, void* d_ws, size_t ws_size,
                              hipStream_t stream) {
    const float* sig   = (const float*)d_in[0];  // [B,C,N,T]
    const float* Wc    = (const float*)d_in[1];  // [T,T]
    const float* alpha = (const float*)d_in[2];  // [N]
    float* out = (float*)d_out;

    float* k   = (float*)d_ws;            // B*C*T   = 131072 floats
    float* kwT = k + BB * CC * TT;        // B*T*C   = 131072 floats
    float* att = kwT + BB * TT * CC;      // B*C*C   = 65536 floats

    k_reduce_kernel<<<BB * CC, 256, 0, stream>>>(sig, alpha, k);
    kw_kernel<<<BB, 256, 0, stream>>>(k, Wc, kwT);
    attn_kernel<<<BB, 256, 0, stream>>>(k, kwT, att);
    mix_kernel<<<dim3(JJ / JT, BB), 256, 0, stream>>>(sig, att, out);
}

// Round 2
// 555.208 us; speedup vs baseline: 1.0888x; 1.0888x over previous
//
#include <hip/hip_runtime.h>
#include <hip/hip_bf16.h>
#include <math.h>

#define BB 16
#define CC 64
#define NN 512
#define TT 128
#define JJ (NN*TT)   // 65536 columns per (b, channel) in the mix view
#define JT 128       // j-tile for mix kernel
#define KP 129       // padded row stride for k tile (conflict-free stride-TT reads)

// ---------------------------------------------------------------------------
// K1: k[b,c,t] = sum_i sig[b,c,i,t] * alpha[i]
// one block per (b,c); 256 threads = 8 i-subgroups x 32 t-quads (float4)
// ---------------------------------------------------------------------------
__global__ __launch_bounds__(256) void k_reduce_kernel(
    const float* __restrict__ sig, const float* __restrict__ alpha,
    float* __restrict__ kout)
{
    __shared__ float aS[NN];
    __shared__ float4 red[8][32];
    const int tid = threadIdx.x;
    for (int x = tid; x < NN; x += 256) aS[x] = alpha[x];
    __syncthreads();

    const int bc = blockIdx.x;
    const float* base = sig + (size_t)bc * (NN * TT);
    const int t4 = tid & 31;   // which float4 of the T=128 row
    const int ig = tid >> 5;   // i-subgroup 0..7

    float4 acc = make_float4(0.f, 0.f, 0.f, 0.f);
    for (int i = ig; i < NN; i += 8) {
        float4 v = *(const float4*)(base + i * TT + t4 * 4);
        const float a = aS[i];
        acc.x = fmaf(v.x, a, acc.x);
        acc.y = fmaf(v.y, a, acc.y);
        acc.z = fmaf(v.z, a, acc.z);
        acc.w = fmaf(v.w, a, acc.w);
    }
    red[ig][t4] = acc;
    __syncthreads();
    if (tid < 32) {
        float4 s = red[0][tid];
        #pragma unroll
        for (int g = 1; g < 8; g++) {
            float4 r = red[g][tid];
            s.x += r.x; s.y += r.y; s.z += r.z; s.w += r.w;
        }
        *(float4*)(kout + (size_t)bc * TT + tid * 4) = s;
    }
}

// ---------------------------------------------------------------------------
// K2 (fused): per (b,c) block:
//   tmp[s]  = sum_t k[b,c,t] * Wc[t,s]          (threads 0..127)
//   sc[d]   = sum_s tmp[s] * k[b,d,s]           (threads 0..63)
//   att[b,c,:] = softmax(sc)                    (wave-0 shuffle reduction)
// grid = B*C = 1024 blocks -> full-device parallelism for the tiny stage.
// ---------------------------------------------------------------------------
__global__ __launch_bounds__(256) void attn_fused_kernel(
    const float* __restrict__ kin, const float* __restrict__ Wc,
    float* __restrict__ att)
{
    __shared__ float kAll[CC * KP];   // k[b] tile, rows padded to 129
    __shared__ float tmp[TT];
    const int tid = threadIdx.x;
    const int b = blockIdx.x >> 6;
    const int c = blockIdx.x & 63;

    const float* kb = kin + b * CC * TT;
    for (int x = tid; x < CC * TT; x += 256)
        kAll[(x >> 7) * KP + (x & 127)] = kb[x];   // coalesced read, seq-bank write
    __syncthreads();

    if (tid < TT) {
        float acc = 0.f;
        const float* kc = &kAll[c * KP];           // wave-uniform -> LDS broadcast
        for (int t = 0; t < TT; t++)
            acc = fmaf(kc[t], Wc[t * TT + tid], acc);  // Wc coalesced per wave
        tmp[tid] = acc;
    }
    __syncthreads();

    if (tid < CC) {                                // exactly wave 0
        float acc = 0.f;
        const float* kd = &kAll[tid * KP];         // stride 129 -> 2-way (free)
        for (int s = 0; s < TT; s++)
            acc = fmaf(tmp[s], kd[s], acc);        // tmp broadcast

        float m = acc;
        #pragma unroll
        for (int off = 32; off >= 1; off >>= 1)
            m = fmaxf(m, __shfl_xor(m, off, 64));
        const float e = __expf(acc - m);
        float sum = e;
        #pragma unroll
        for (int off = 32; off >= 1; off >>= 1)
            sum += __shfl_xor(sum, off, 64);
        att[b * CC * CC + c * CC + tid] = e / sum;
    }
}

// ---------------------------------------------------------------------------
// K3: out[b][c][j] = sum_i att[b][c][i] * sig[b][i][j],  j = n*T + t flattened
// grid = (JJ/JT, B); block 256. LDS: attT[i][c] (transposed, so each thread's
// 4 att weights per i are ONE ds_read_b128) + sig tile 64xJT.
// Each thread: 4c x 8j register tile (32 accumulators).
// ---------------------------------------------------------------------------
__global__ __launch_bounds__(256) void mix_kernel(
    const float* __restrict__ sig, const float* __restrict__ att,
    float* __restrict__ out)
{
    __shared__ float attT[CC * CC];      // [i][c], 16 KiB
    __shared__ float stile[CC][JT];      // 32 KiB
    const int b = blockIdx.y;
    const int jbase = blockIdx.x * JT;
    const int tid = threadIdx.x;

    const float* ab = att + b * CC * CC;
    for (int x = tid; x < CC * CC; x += 256)
        attT[(x & 63) * CC + (x >> 6)] = ab[x];   // coalesced read, transposed store

    const float* sb = sig + (size_t)b * CC * JJ + jbase;
    for (int x = tid; x < CC * JT / 4; x += 256) {
        const int i = x >> 5;   // JT/4 = 32 quads per row
        const int q = x & 31;
        *(float4*)(&stile[i][q * 4]) = *(const float4*)(sb + (size_t)i * JJ + q * 4);
    }
    __syncthreads();

    const int tc = tid >> 4;   // 0..15 -> channels 4*tc .. 4*tc+3
    const int tj = tid & 15;   // quads tj and tj+16

    float4 acc[4][2];
    #pragma unroll
    for (int q = 0; q < 4; q++) {
        acc[q][0] = make_float4(0.f, 0.f, 0.f, 0.f);
        acc[q][1] = make_float4(0.f, 0.f, 0.f, 0.f);
    }

    #pragma unroll 4
    for (int i = 0; i < CC; i++) {
        const float4 a4 = *(const float4*)(&attT[i * CC + 4 * tc]);  // 1 b128
        const float a[4] = {a4.x, a4.y, a4.z, a4.w};
        #pragma unroll
        for (int u = 0; u < 2; u++) {
            const float4 s = *(const float4*)(&stile[i][(tj + 16 * u) * 4]);
            #pragma unroll
            for (int q = 0; q < 4; q++) {
                acc[q][u].x = fmaf(a[q], s.x, acc[q][u].x);
                acc[q][u].y = fmaf(a[q], s.y, acc[q][u].y);
                acc[q][u].z = fmaf(a[q], s.z, acc[q][u].z);
                acc[q][u].w = fmaf(a[q], s.w, acc[q][u].w);
            }
        }
    }

    float* ob = out + (size_t)b * CC * JJ + jbase;
    #pragma unroll
    for (int q = 0; q < 4; q++) {
        const int c = 4 * tc + q;
        #pragma unroll
        for (int u = 0; u < 2; u++)
            *(float4*)(ob + (size_t)c * JJ + (tj + 16 * u) * 4) = acc[q][u];
    }
}

// ---------------------------------------------------------------------------
extern "C" void kernel_launch(void* const* d_in, const int* in_sizes, int n_in,
                              void* d_out, int out_size, void* d_ws, size_t ws_size,
                              hipStream_t stream) {
    const float* sig   = (const float*)d_in[0];  // [B,C,N,T]
    const float* Wc    = (const float*)d_in[1];  // [T,T]
    const float* alpha = (const float*)d_in[2];  // [N]
    float* out = (float*)d_out;

    float* k   = (float*)d_ws;            // B*C*T = 131072 floats
    float* att = k + BB * CC * TT;        // B*C*C = 65536 floats

    k_reduce_kernel<<<BB * CC, 256, 0, stream>>>(sig, alpha, k);
    attn_fused_kernel<<<BB * CC, 256, 0, stream>>>(k, Wc, att);
    mix_kernel<<<dim3(JJ / JT, BB), 256, 0, stream>>>(sig, att, out);
}